// Round 4
// baseline (427.422 us; speedup 1.0000x reference)
//
#include <hip/hip_runtime.h>

// Perona-Malik diffusion step, fp32, NCHW (64,1,1024,1024).
// One wave == one full 1024-px row (16 px/thread, 4x f32x4).
// Column halos via __shfl from neighbor lanes; at lanes 0/63 the reflect
// index maps back into the lane's own registers (x=-1 -> 1, 1024 -> 1022),
// so there are ZERO halo loads. Rolling 4-buffer register window, unroll-4
// (static names, no rotation movs), prefetch row y+2 while computing row y.

#define IMG_H 1024
#define IMG_W 1024
#define N_IMG 64
#define RPW 16                 // rows per wave
#define WPB 4                  // waves per block
#define RPB (RPW * WPB)        // 64 rows per block
#define BPI (IMG_H / RPB)      // 16 blocks per image

typedef float f32x4 __attribute__((ext_vector_type(4)));

// v[0] = left halo, v[1..16] = 16 owned px, v[17] = right halo
__device__ __forceinline__ void load_row(const float* __restrict__ row, int x0,
                                         float v[18]) {
#pragma unroll
    for (int q = 0; q < 4; ++q) {
        const f32x4 m = *reinterpret_cast<const f32x4*>(row + x0 + q * 4);
        v[1 + q * 4 + 0] = m.x;
        v[1 + q * 4 + 1] = m.y;
        v[1 + q * 4 + 2] = m.z;
        v[1 + q * 4 + 3] = m.w;
    }
}

__device__ __forceinline__ void make_halo(float v[18], int lane) {
    const float l = __shfl_up(v[16], 1);     // lane-1's px15
    const float r = __shfl_down(v[1], 1);    // lane+1's px0
    v[0]  = (lane == 0)  ? v[2]  : l;        // reflect: x=-1   -> x=1
    v[17] = (lane == 63) ? v[15] : r;        // reflect: x=1024 -> x=1022
}

__device__ __forceinline__ void compute_store(const float A[18], const float B[18],
                                              const float C[18], const float* k,
                                              float* __restrict__ op) {
#pragma unroll
    for (int q = 0; q < 4; ++q) {
        f32x4 o;
#pragma unroll
        for (int e = 0; e < 4; ++e) {
            const int j = q * 4 + e;         // px j lives at v[j+1]
            float g = k[0] * A[j] + k[1] * A[j + 1] + k[2] * A[j + 2]
                    + k[3] * B[j] + k[4] * B[j + 1] + k[5] * B[j + 2]
                    + k[6] * C[j] + k[7] * C[j + 1] + k[8] * C[j + 2];
            float coeff = __expf(-100.0f * g * g);     // exp(-g^2/0.01)
            float val = B[j + 1] + g * coeff * 0.15f;
            o[e] = fminf(fmaxf(val, 0.0f), 1.0f);
        }
        __builtin_nontemporal_store(o, reinterpret_cast<f32x4*>(op + q * 4));
    }
}

__global__ __launch_bounds__(256, 4)
void perona_malik_kernel(const float* __restrict__ img,
                         const float* __restrict__ lap,
                         float* __restrict__ out) {
    float k[9];
#pragma unroll
    for (int i = 0; i < 9; ++i) k[i] = lap[i];   // uniform -> scalar loads

    const int lane = threadIdx.x & 63;
    const int wave = threadIdx.x >> 6;
    const int n    = blockIdx.x / BPI;
    const int blk  = blockIdx.x % BPI;
    const int y0   = blk * RPB + wave * RPW;
    const int x0   = lane * 16;                  // 64B-aligned

    const float* __restrict__ base  = img + (size_t)n * IMG_H * IMG_W;
    float*       __restrict__ obase = out + (size_t)n * IMG_H * IMG_W;

    float r0[18], r1[18], r2[18], r3[18];
    {
        const int ym = (y0 == 0) ? 1 : (y0 - 1);     // reflect top edge
        load_row(base + (size_t)ym * IMG_W, x0, r0);
        load_row(base + (size_t)y0 * IMG_W, x0, r1);
        load_row(base + (size_t)(y0 + 1) * IMG_W, x0, r2);  // y0+1 <= 1009 < H
        make_halo(r0, lane);
        make_halo(r1, lane);
    }

    // Per step: issue D's prefetch FIRST, then halo-finalize C (vmcnt waits on
    // C's loads only -- issued one step earlier), then compute from registers.
#define STEP(A, B, C, D, I)                                                    \
    {                                                                          \
        if ((I) < RPW - 1) {                                                   \
            int t = y0 + (I) + 2;                                              \
            if (t >= IMG_H) t = IMG_H - 2;         /* reflect bottom edge */   \
            load_row(base + (size_t)t * IMG_W, x0, D);                         \
        }                                                                      \
        make_halo(C, lane);                                                    \
        compute_store(A, B, C, k, obase + (size_t)(y0 + (I)) * IMG_W + x0);    \
    }

    for (int i = 0; i < RPW; i += 4) {      // 4 iters, static buffer rotation
        STEP(r0, r1, r2, r3, i + 0)
        STEP(r1, r2, r3, r0, i + 1)
        STEP(r2, r3, r0, r1, i + 2)
        STEP(r3, r0, r1, r2, i + 3)
    }
#undef STEP
}

extern "C" void kernel_launch(void* const* d_in, const int* in_sizes, int n_in,
                              void* d_out, int out_size, void* d_ws, size_t ws_size,
                              hipStream_t stream) {
    const float* img = (const float*)d_in[0];
    const float* lap = (const float*)d_in[1];
    float*       out = (float*)d_out;

    const int blocks = N_IMG * BPI;   // 1024 blocks = 4 blocks/CU, one round
    perona_malik_kernel<<<blocks, 256, 0, stream>>>(img, lap, out);
}

// Round 5
// 87.158 us; speedup vs baseline: 4.9040x; 4.9040x over previous
//
#include <hip/hip_runtime.h>

// Perona-Malik diffusion step, fp32, NCHW (64,1,1024,1024).
// R3 skeleton (4 px/thread contiguous, one block per 1024-px row stripe,
// 2048 blocks = 32 waves/CU) + depth-2 prefetch, 2 rows per iteration:
// issue loads for rows y+3,y+4 while computing rows y,y+1 from registers.
// Memory-bound target: ~395 MB effective traffic -> ~65-80 us.

#define IMG_H 1024
#define IMG_W 1024
#define N_IMG 64
#define ROWS_PER_BLOCK 32
#define STRIPES (IMG_H / ROWS_PER_BLOCK)   // 32

typedef float f32x4 __attribute__((ext_vector_type(4)));

// v[0]=left halo, v[1..4]=4 owned px (aligned vec load), v[5]=right halo
__device__ __forceinline__ void load_row6(const float* __restrict__ row,
                                          int x0, float v[6]) {
    const f32x4 m = *reinterpret_cast<const f32x4*>(row + x0);
    v[1] = m.x; v[2] = m.y; v[3] = m.z; v[4] = m.w;
    int xl = x0 - 1;       if (xl < 0)      xl = 1;            // reflect
    int xr = x0 + 4;       if (xr >= IMG_W) xr = IMG_W - 2;    // reflect
    v[0] = row[xl];        // L1 hit (same lines as the wave's vec loads)
    v[5] = row[xr];
}

__device__ __forceinline__ void compute_store(const float A[6], const float B[6],
                                              const float C[6], const float* k,
                                              float* __restrict__ op) {
    f32x4 res;
#pragma unroll
    for (int i = 0; i < 4; ++i) {
        float g = k[0] * A[i] + k[1] * A[i + 1] + k[2] * A[i + 2]
                + k[3] * B[i] + k[4] * B[i + 1] + k[5] * B[i + 2]
                + k[6] * C[i] + k[7] * C[i + 1] + k[8] * C[i + 2];
        float coeff = __expf(-100.0f * g * g);        // exp(-g^2/0.01)
        float v = B[i + 1] + g * coeff * 0.15f;
        res[i] = fminf(fmaxf(v, 0.0f), 1.0f);
    }
    __builtin_nontemporal_store(res, reinterpret_cast<f32x4*>(op));
}

__global__ __launch_bounds__(256, 4)
void perona_malik_kernel(const float* __restrict__ img,
                         const float* __restrict__ lap,
                         float* __restrict__ out) {
    float k[9];
#pragma unroll
    for (int i = 0; i < 9; ++i) k[i] = lap[i];

    const int tid  = threadIdx.x;
    const int x0   = tid * 4;                  // 4 px/thread, 16B aligned
    const int n    = blockIdx.x / STRIPES;
    const int strp = blockIdx.x % STRIPES;

    const float* __restrict__ base  = img + (size_t)n * IMG_H * IMG_W;
    float*       __restrict__ obase = out + (size_t)n * IMG_H * IMG_W;

    const int y0   = strp * ROWS_PER_BLOCK;
    const int yend = y0 + ROWS_PER_BLOCK;

    // rolling window: a=row(y-1) b=row(y) c=row(y+1) d=row(y+2);
    // e,f = prefetch of rows y+3, y+4 (consumed as c,d next iteration)
    float a[6], b[6], c[6], d[6], e[6], f[6];
    {
        const int ym = (y0 == 0) ? 1 : (y0 - 1);       // reflect top edge
        load_row6(base + (size_t)ym * IMG_W, x0, a);
        load_row6(base + (size_t)y0 * IMG_W, x0, b);
        load_row6(base + (size_t)(y0 + 1) * IMG_W, x0, c);  // y0+1 <= 993 < H
        load_row6(base + (size_t)(y0 + 2) * IMG_W, x0, d);  // y0+2 <= 994 < H
    }

    for (int y = y0; y < yend; y += 2) {
        // depth-2 prefetch: rows y+3, y+4 (guarded; reflect only hits t==H)
        const int t1 = y + 3, t2 = y + 4;
        if (t1 <= yend)                                  // t1 odd, never ==H
            load_row6(base + (size_t)t1 * IMG_W, x0, e);
        if (t2 <= yend) {
            int tt = (t2 >= IMG_H) ? (IMG_H - 2) : t2;   // reflect bottom edge
            load_row6(base + (size_t)tt * IMG_W, x0, f);
        }

        compute_store(a, b, c, k, obase + (size_t)y * IMG_W + x0);
        compute_store(b, c, d, k, obase + (size_t)(y + 1) * IMG_W + x0);

        // rotate window by 2 rows (cheap v_movs, static names)
#pragma unroll
        for (int i = 0; i < 6; ++i) { a[i] = c[i]; b[i] = d[i]; c[i] = e[i]; d[i] = f[i]; }
    }
}

extern "C" void kernel_launch(void* const* d_in, const int* in_sizes, int n_in,
                              void* d_out, int out_size, void* d_ws, size_t ws_size,
                              hipStream_t stream) {
    const float* img = (const float*)d_in[0];
    const float* lap = (const float*)d_in[1];
    float*       out = (float*)d_out;

    const int blocks = N_IMG * STRIPES;   // 2048 blocks = 32 waves/CU
    perona_malik_kernel<<<blocks, 256, 0, stream>>>(img, lap, out);
}